// Round 1
// baseline (615.907 us; speedup 1.0000x reference)
//
#include <hip/hip_runtime.h>
#include <cstdint>

typedef __attribute__((ext_vector_type(8))) __bf16 bf16x8;
typedef __attribute__((ext_vector_type(4))) __bf16 bf16x4;
typedef __attribute__((ext_vector_type(4))) float f32x4;

#define MFMA16(a, b, c) __builtin_amdgcn_mfma_f32_16x16x32_bf16((a), (b), (c), 0, 0, 0)

static constexpr int SEQ = 2048;
static constexpr int DQ = 128;
static constexpr int DV = 256;
static constexpr float QK_SCALE = 4.5f;  // qk / INV_SCALE, INV_SCALE = 1/(0.5*9)

__device__ __forceinline__ bf16x4 cvt4(float4 v) {
    bf16x4 y;
    y[0] = (__bf16)v.x; y[1] = (__bf16)v.y; y[2] = (__bf16)v.z; y[3] = (__bf16)v.w;
    return y;
}

// ---------------------------------------------------------------------------
// Projection GEMM: out[m][n] (or transposed [b][n][s]) = scale * X[m][:K] . W[n][:K]
// X: [16384][K] fp32, W: [128][K] fp32 (torch-style [out,in] => A@B^T, both
// operands K-contiguous). 64-row tile per wg, 4 waves x 16 rows, bf16 output.
// ---------------------------------------------------------------------------
template <int K, int TRANS>
__global__ __launch_bounds__(256) void k_proj(const float* __restrict__ X,
                                              const float* __restrict__ W,
                                              __bf16* __restrict__ out,
                                              float outScale) {
    __shared__ __bf16 ldsX[64][136];   // 272B rows: 16B-aligned, banks spread by 4
    __shared__ __bf16 ldsW[128][136];

    const int t = threadIdx.x;
    const int m0 = blockIdx.x * 64;
    const int w = t >> 6, l = t & 63, lrow = l & 15, lq = l >> 4;

    f32x4 acc[8];
#pragma unroll
    for (int i = 0; i < 8; ++i) acc[i] = f32x4{0.f, 0.f, 0.f, 0.f};

#pragma unroll
    for (int kh = 0; kh < K / 128; ++kh) {
        if (kh) __syncthreads();
        // stage X block 64x128 fp32 -> bf16
#pragma unroll
        for (int i = 0; i < 8; ++i) {
            int idx = t + i * 256;
            int r = idx >> 5, c4 = idx & 31;
            float4 v = *(const float4*)(X + (size_t)(m0 + r) * K + kh * 128 + c4 * 4);
            *(bf16x4*)&ldsX[r][c4 * 4] = cvt4(v);
        }
        // stage W block 128x128 fp32 -> bf16
#pragma unroll
        for (int i = 0; i < 16; ++i) {
            int idx = t + i * 256;
            int r = idx >> 5, c4 = idx & 31;
            float4 v = *(const float4*)(W + (size_t)r * K + kh * 128 + c4 * 4);
            *(bf16x4*)&ldsW[r][c4 * 4] = cvt4(v);
        }
        __syncthreads();

        bf16x8 aA[4];
#pragma unroll
        for (int kc = 0; kc < 4; ++kc)
            aA[kc] = *(const bf16x8*)((const char*)&ldsX[w * 16 + lrow][0] + kc * 64 + lq * 16);
#pragma unroll
        for (int nt = 0; nt < 8; ++nt) {
#pragma unroll
            for (int kc = 0; kc < 4; ++kc) {
                bf16x8 bB = *(const bf16x8*)((const char*)&ldsW[nt * 16 + lrow][0] + kc * 64 + lq * 16);
                acc[nt] = MFMA16(aA[kc], bB, acc[nt]);
            }
        }
    }

#pragma unroll
    for (int nt = 0; nt < 8; ++nt) {
#pragma unroll
        for (int j = 0; j < 4; ++j) {
            int gm = m0 + w * 16 + lq * 4 + j;   // C/D layout: row=(lane>>4)*4+reg
            int col = nt * 16 + lrow;            //             col=lane&15
            float v = acc[nt][j] * outScale;
            if (TRANS) {
                int b = gm >> 11, s = gm & 2047;
                out[((size_t)b * 128 + col) * SEQ + s] = (__bf16)v;
            } else {
                out[(size_t)gm * 128 + col] = (__bf16)v;
            }
        }
    }
}

// ---------------------------------------------------------------------------
// value [8][2048][256] fp32  ->  vt [8][256][2048] bf16 (tiled 64x64 transpose)
// ---------------------------------------------------------------------------
__global__ __launch_bounds__(256) void k_vt(const float* __restrict__ V, __bf16* __restrict__ vt) {
    __shared__ __bf16 tile[64][72];
    const int t = threadIdx.x;
    const int b = blockIdx.z, s0 = blockIdx.x * 64, v0 = blockIdx.y * 64;
#pragma unroll
    for (int i = 0; i < 4; ++i) {
        int idx = t + i * 256;
        int r = idx >> 4, c4 = idx & 15;
        float4 x = *(const float4*)(V + ((size_t)b * SEQ + s0 + r) * DV + v0 + c4 * 4);
        *(bf16x4*)&tile[r][c4 * 4] = cvt4(x);
    }
    __syncthreads();
#pragma unroll
    for (int i = 0; i < 4; ++i) {
        int idx = t + i * 256;
        int v = idx >> 4, c4 = idx & 15;
        bf16x4 y;
        y[0] = tile[c4 * 4 + 0][v]; y[1] = tile[c4 * 4 + 1][v];
        y[2] = tile[c4 * 4 + 2][v]; y[3] = tile[c4 * 4 + 3][v];
        *(bf16x4*)(vt + ((size_t)b * DV + v0 + v) * SEQ + s0 + c4 * 4) = y;
    }
}

__global__ __launch_bounds__(256) void k_cvt_bf16(const float* __restrict__ src,
                                                  __bf16* __restrict__ dst, int n4) {
    int i = blockIdx.x * 256 + threadIdx.x;
    if (i < n4) {
        float4 v = *(const float4*)(src + (size_t)i * 4);
        *(bf16x4*)(dst + (size_t)i * 4) = cvt4(v);
    }
}

// ---------------------------------------------------------------------------
// Flash attention: v1[b][q][o] = softmax_k(r1.r2^T) @ r3    (scale folded in r1)
// wg = 4 waves, 64 q-rows; KT=64 k-cols/iter; online softmax per C-layout row.
// ---------------------------------------------------------------------------
__global__ __launch_bounds__(256) void k_flash(const __bf16* __restrict__ r1s,
                                               const __bf16* __restrict__ r2,
                                               const __bf16* __restrict__ r3t,
                                               __bf16* __restrict__ v1) {
    __shared__ __bf16 r2lds[64][136];   // [kcol][d], 272B rows
    __shared__ __bf16 r3lds[128][72];   // [o][k],    144B rows
    __shared__ __bf16 plds[4][16][72];  // per-wave P round-trip (C->A layout)

    const int t = threadIdx.x;
    const int bx = blockIdx.x;
    const int b = bx >> 5;
    const int q0 = (bx & 31) * 64;
    const int w = t >> 6, l = t & 63, lrow = l & 15, lq = l >> 4;

    const __bf16* r1b = r1s + (size_t)b * SEQ * 128;
    const __bf16* r2b = r2 + (size_t)b * SEQ * 128;
    const __bf16* r3b = r3t + (size_t)b * 128 * SEQ;

    // resident A-fragments of r1 (q rows of this wave), direct from global
    bf16x8 aQ[4];
    {
        const __bf16* p = r1b + (size_t)(q0 + w * 16 + lrow) * 128 + lq * 8;
#pragma unroll
        for (int kc = 0; kc < 4; ++kc) aQ[kc] = *(const bf16x8*)(p + kc * 32);
    }

    f32x4 acc[8];
#pragma unroll
    for (int i = 0; i < 8; ++i) acc[i] = f32x4{0.f, 0.f, 0.f, 0.f};
    float mrow[4] = {-INFINITY, -INFINITY, -INFINITY, -INFINITY};
    float lsum[4] = {0.f, 0.f, 0.f, 0.f};

    // staging: r2 tile 64x128 (64B/thread), r3t tile 128x64 (64B/thread)
    const __bf16* gr2 = r2b + (size_t)(t >> 2) * 128 + (t & 3) * 32;
    const __bf16* gr3 = r3b + (size_t)(t >> 1) * SEQ + (t & 1) * 32;
    char* sr2 = (char*)&r2lds[t >> 2][(t & 3) * 32];
    char* sr3 = (char*)&r3lds[t >> 1][(t & 1) * 32];

    uint4 sa[4], sb[4];
#pragma unroll
    for (int i = 0; i < 4; ++i) {
        sa[i] = *(const uint4*)((const char*)gr2 + i * 16);
        sb[i] = *(const uint4*)((const char*)gr3 + i * 16);
    }

    for (int it = 0; it < 32; ++it) {
#pragma unroll
        for (int i = 0; i < 4; ++i) {
            *(uint4*)(sr2 + i * 16) = sa[i];
            *(uint4*)(sr3 + i * 16) = sb[i];
        }
        __syncthreads();
        if (it + 1 < 32) {  // prefetch next tile into regs (overlaps compute)
            const __bf16* ga = gr2 + (size_t)(it + 1) * 64 * 128;
            const __bf16* gb = gr3 + (it + 1) * 64;
#pragma unroll
            for (int i = 0; i < 4; ++i) {
                sa[i] = *(const uint4*)((const char*)ga + i * 16);
                sb[i] = *(const uint4*)((const char*)gb + i * 16);
            }
        }

        // S = r1 . r2^T  (16q x 64k per wave)
        f32x4 sc[4];
#pragma unroll
        for (int ct = 0; ct < 4; ++ct) {
            f32x4 s = f32x4{0.f, 0.f, 0.f, 0.f};
#pragma unroll
            for (int kc = 0; kc < 4; ++kc) {
                bf16x8 bb = *(const bf16x8*)((const char*)&r2lds[ct * 16 + lrow][0] + kc * 64 + lq * 16);
                s = MFMA16(aQ[kc], bb, s);
            }
            sc[ct] = s;
        }

        // ---- online softmax (rows live in lanes sharing lane>>4) ----
        float pm[4], ps[4], al[4];
#pragma unroll
        for (int j = 0; j < 4; ++j)
            pm[j] = fmaxf(fmaxf(sc[0][j], sc[1][j]), fmaxf(sc[2][j], sc[3][j]));
#pragma unroll
        for (int off = 1; off <= 8; off <<= 1)
#pragma unroll
            for (int j = 0; j < 4; ++j) pm[j] = fmaxf(pm[j], __shfl_xor(pm[j], off, 64));
#pragma unroll
        for (int j = 0; j < 4; ++j) {
            float mn = fmaxf(mrow[j], pm[j]);
            al[j] = __expf(mrow[j] - mn);
            mrow[j] = mn;
            ps[j] = 0.f;
        }
        float pr[4][4];
#pragma unroll
        for (int ct = 0; ct < 4; ++ct)
#pragma unroll
            for (int j = 0; j < 4; ++j) {
                float p = __expf(sc[ct][j] - mrow[j]);
                pr[ct][j] = p;
                ps[j] += p;
            }
#pragma unroll
        for (int off = 1; off <= 8; off <<= 1)
#pragma unroll
            for (int j = 0; j < 4; ++j) ps[j] += __shfl_xor(ps[j], off, 64);
#pragma unroll
        for (int j = 0; j < 4; ++j) lsum[j] = lsum[j] * al[j] + ps[j];
#pragma unroll
        for (int ot = 0; ot < 8; ++ot)
#pragma unroll
            for (int j = 0; j < 4; ++j) acc[ot][j] *= al[j];

        // P: C-layout -> LDS -> A-layout (wave-local region)
#pragma unroll
        for (int ct = 0; ct < 4; ++ct)
#pragma unroll
            for (int j = 0; j < 4; ++j)
                plds[w][lq * 4 + j][ct * 16 + lrow] = (__bf16)pr[ct][j];
        __builtin_amdgcn_s_waitcnt(0xc07f);  // lgkmcnt(0) only, leave vmcnt free

        bf16x8 pA[2];
#pragma unroll
        for (int kc = 0; kc < 2; ++kc)
            pA[kc] = *(const bf16x8*)((const char*)&plds[w][lrow][0] + kc * 64 + lq * 16);
#pragma unroll
        for (int ot = 0; ot < 8; ++ot) {
#pragma unroll
            for (int kc = 0; kc < 2; ++kc) {
                bf16x8 bb = *(const bf16x8*)((const char*)&r3lds[ot * 16 + lrow][0] + kc * 64 + lq * 16);
                acc[ot] = MFMA16(pA[kc], bb, acc[ot]);
            }
        }
        __syncthreads();
    }

#pragma unroll
    for (int ot = 0; ot < 8; ++ot)
#pragma unroll
        for (int j = 0; j < 4; ++j) {
            int q = q0 + w * 16 + lq * 4 + j;
            float v = acc[ot][j] / lsum[j];
            v1[((size_t)b * SEQ + q) * 128 + ot * 16 + lrow] = (__bf16)v;
        }
}

// ---------------------------------------------------------------------------
// out[b][q][v] = mask[b][q][:] @ value[:,v]  +  v1[b][q][:] @ Wout[v][:]
// wg: 64 q-rows x 256 v-cols; mask fp32 staged to LDS, cvt at fragment build.
// ---------------------------------------------------------------------------
__global__ __launch_bounds__(256) void k_out(const float* __restrict__ mask,
                                             const __bf16* __restrict__ vtb,
                                             const __bf16* __restrict__ v1,
                                             const __bf16* __restrict__ wob,
                                             float* __restrict__ out) {
    __shared__ float mlds[64][36];      // [q][k] fp32, 144B rows
    __shared__ __bf16 vtlds[256][32];   // [v][k] bf16, 64B rows (bank-balanced)

    const int t = threadIdx.x;
    const int m0 = blockIdx.x * 64;
    const int b = m0 >> 11, q0 = m0 & 2047;
    const int w = t >> 6, l = t & 63, lrow = l & 15, lq = l >> 4;

    f32x4 acc[16];
#pragma unroll
    for (int i = 0; i < 16; ++i) acc[i] = f32x4{0.f, 0.f, 0.f, 0.f};

    const float* gm = mask + ((size_t)b * SEQ + q0 + (t >> 2)) * SEQ + (t & 3) * 8;
    const __bf16* gv = vtb + ((size_t)b * DV + t) * SEQ;
    char* sm = (char*)&mlds[t >> 2][(t & 3) * 8];
    char* sv = (char*)&vtlds[t][0];

    uint4 stm[2], stv[4];
#pragma unroll
    for (int i = 0; i < 2; ++i) stm[i] = *(const uint4*)((const char*)gm + i * 16);
#pragma unroll
    for (int i = 0; i < 4; ++i) stv[i] = *(const uint4*)((const char*)gv + i * 16);

    for (int it = 0; it < 64; ++it) {
#pragma unroll
        for (int i = 0; i < 2; ++i) *(uint4*)(sm + i * 16) = stm[i];
#pragma unroll
        for (int i = 0; i < 4; ++i) *(uint4*)(sv + i * 16) = stv[i];
        __syncthreads();
        if (it + 1 < 64) {
            int k0 = (it + 1) * 32;
#pragma unroll
            for (int i = 0; i < 2; ++i) stm[i] = *(const uint4*)((const char*)(gm + k0) + i * 16);
#pragma unroll
            for (int i = 0; i < 4; ++i) stv[i] = *(const uint4*)((const char*)(gv + k0) + i * 16);
        }
        // mask A-fragment: 8 consecutive fp32 -> bf16
        float4 a0 = *(const float4*)((const char*)&mlds[w * 16 + lrow][0] + lq * 32);
        float4 a1 = *(const float4*)((const char*)&mlds[w * 16 + lrow][0] + lq * 32 + 16);
        bf16x8 aM;
        aM[0] = (__bf16)a0.x; aM[1] = (__bf16)a0.y; aM[2] = (__bf16)a0.z; aM[3] = (__bf16)a0.w;
        aM[4] = (__bf16)a1.x; aM[5] = (__bf16)a1.y; aM[6] = (__bf16)a1.z; aM[7] = (__bf16)a1.w;
#pragma unroll
        for (int vt16 = 0; vt16 < 16; ++vt16) {
            bf16x8 bb = *(const bf16x8*)((const char*)&vtlds[vt16 * 16 + lrow][0] + lq * 16);
            acc[vt16] = MFMA16(aM, bb, acc[vt16]);
        }
        __syncthreads();
    }

    // epilogue: + v1 @ Wout^T (operands direct from global, small volume)
    bf16x8 aV[4];
#pragma unroll
    for (int oc = 0; oc < 4; ++oc)
        aV[oc] = *(const bf16x8*)(v1 + (size_t)(m0 + w * 16 + lrow) * 128 + oc * 32 + lq * 8);
#pragma unroll
    for (int vt16 = 0; vt16 < 16; ++vt16) {
#pragma unroll
        for (int oc = 0; oc < 4; ++oc) {
            bf16x8 bb = *(const bf16x8*)(wob + (size_t)(vt16 * 16 + lrow) * 128 + oc * 32 + lq * 8);
            acc[vt16] = MFMA16(aV[oc], bb, acc[vt16]);
        }
    }

#pragma unroll
    for (int vt16 = 0; vt16 < 16; ++vt16)
#pragma unroll
        for (int j = 0; j < 4; ++j) {
            int gq = m0 + w * 16 + lq * 4 + j;
            out[(size_t)gq * 256 + vt16 * 16 + lrow] = acc[vt16][j];
        }
}

// ---------------------------------------------------------------------------
extern "C" void kernel_launch(void* const* d_in, const int* in_sizes, int n_in,
                              void* d_out, int out_size, void* d_ws, size_t ws_size,
                              hipStream_t stream) {
    const float* q    = (const float*)d_in[0];
    const float* k    = (const float*)d_in[1];
    const float* v    = (const float*)d_in[2];
    const float* mask = (const float*)d_in[3];
    const float* W0   = (const float*)d_in[4];
    const float* W1   = (const float*)d_in[5];
    const float* W2   = (const float*)d_in[6];
    const float* Wout = (const float*)d_in[7];
    float* out = (float*)d_out;

    char* ws = (char*)d_ws;
    __bf16* r1s = (__bf16*)(ws);                       // [8][2048][128] bf16, 4MB (pre-scaled 4.5)
    __bf16* r2b = (__bf16*)(ws + (4ull << 20));        // [8][2048][128] bf16, 4MB
    __bf16* r3t = (__bf16*)(ws + (8ull << 20));        // [8][128][2048] bf16, 4MB (transposed)
    __bf16* vtb = (__bf16*)(ws + (12ull << 20));       // [8][256][2048] bf16, 8MB (transposed)
    __bf16* wob = (__bf16*)(ws + (20ull << 20));       // [256][128] bf16, 64KB
    __bf16* v1b = (__bf16*)(ws + (21ull << 20));       // [8][2048][128] bf16, 4MB

    k_proj<128, 0><<<256, 256, 0, stream>>>(q, W0, r1s, QK_SCALE);
    k_proj<128, 0><<<256, 256, 0, stream>>>(k, W1, r2b, 1.0f);
    k_proj<256, 1><<<256, 256, 0, stream>>>(v, W2, r3t, 1.0f);
    k_vt<<<dim3(32, 4, 8), 256, 0, stream>>>(v, vtb);
    k_cvt_bf16<<<32, 256, 0, stream>>>(Wout, wob, 8192);
    k_flash<<<256, 256, 0, stream>>>(r1s, r2b, r3t, v1b);
    k_out<<<256, 256, 0, stream>>>(mask, vtb, v1b, wob, out);
}

// Round 2
// 411.325 us; speedup vs baseline: 1.4974x; 1.4974x over previous
//
#include <hip/hip_runtime.h>
#include <cstdint>

typedef __attribute__((ext_vector_type(8))) __bf16 bf16x8;
typedef __attribute__((ext_vector_type(4))) __bf16 bf16x4;
typedef __attribute__((ext_vector_type(4))) float f32x4;

#define MFMA16(a, b, c) __builtin_amdgcn_mfma_f32_16x16x32_bf16((a), (b), (c), 0, 0, 0)

static constexpr int SEQ = 2048;
static constexpr int DV = 256;
static constexpr float QK_SCALE = 4.5f;  // qk / INV_SCALE, INV_SCALE = 1/(0.5*9)

__device__ __forceinline__ bf16x4 cvt4(float4 v) {
    bf16x4 y;
    y[0] = (__bf16)v.x; y[1] = (__bf16)v.y; y[2] = (__bf16)v.z; y[3] = (__bf16)v.w;
    return y;
}

// async global->LDS DMA, 16B per lane; LDS dest must be wave-uniform base,
// lane i lands at base + i*16 (no padding possible -> use source-side XOR swizzle)
__device__ __forceinline__ void gl_lds16(const void* g, void* l) {
    __builtin_amdgcn_global_load_lds((const __attribute__((address_space(1))) uint32_t*)g,
                                     (__attribute__((address_space(3))) uint32_t*)l, 16, 0, 0);
}

// ---------------------------------------------------------------------------
// Projection GEMM (unchanged from round 0 — known correct)
// ---------------------------------------------------------------------------
template <int K, int TRANS>
__global__ __launch_bounds__(256) void k_proj(const float* __restrict__ X,
                                              const float* __restrict__ W,
                                              __bf16* __restrict__ out,
                                              float outScale) {
    __shared__ __bf16 ldsX[64][136];
    __shared__ __bf16 ldsW[128][136];

    const int t = threadIdx.x;
    const int m0 = blockIdx.x * 64;
    const int w = t >> 6, l = t & 63, lrow = l & 15, lq = l >> 4;

    f32x4 acc[8];
#pragma unroll
    for (int i = 0; i < 8; ++i) acc[i] = f32x4{0.f, 0.f, 0.f, 0.f};

#pragma unroll
    for (int kh = 0; kh < K / 128; ++kh) {
        if (kh) __syncthreads();
#pragma unroll
        for (int i = 0; i < 8; ++i) {
            int idx = t + i * 256;
            int r = idx >> 5, c4 = idx & 31;
            float4 v = *(const float4*)(X + (size_t)(m0 + r) * K + kh * 128 + c4 * 4);
            *(bf16x4*)&ldsX[r][c4 * 4] = cvt4(v);
        }
#pragma unroll
        for (int i = 0; i < 16; ++i) {
            int idx = t + i * 256;
            int r = idx >> 5, c4 = idx & 31;
            float4 v = *(const float4*)(W + (size_t)r * K + kh * 128 + c4 * 4);
            *(bf16x4*)&ldsW[r][c4 * 4] = cvt4(v);
        }
        __syncthreads();

        bf16x8 aA[4];
#pragma unroll
        for (int kc = 0; kc < 4; ++kc)
            aA[kc] = *(const bf16x8*)((const char*)&ldsX[w * 16 + lrow][0] + kc * 64 + lq * 16);
#pragma unroll
        for (int nt = 0; nt < 8; ++nt) {
#pragma unroll
            for (int kc = 0; kc < 4; ++kc) {
                bf16x8 bB = *(const bf16x8*)((const char*)&ldsW[nt * 16 + lrow][0] + kc * 64 + lq * 16);
                acc[nt] = MFMA16(aA[kc], bB, acc[nt]);
            }
        }
    }

#pragma unroll
    for (int nt = 0; nt < 8; ++nt) {
#pragma unroll
        for (int j = 0; j < 4; ++j) {
            int gm = m0 + w * 16 + lq * 4 + j;
            int col = nt * 16 + lrow;
            float v = acc[nt][j] * outScale;
            if (TRANS) {
                int b = gm >> 11, s = gm & 2047;
                out[((size_t)b * 128 + col) * SEQ + s] = (__bf16)v;
            } else {
                out[(size_t)gm * 128 + col] = (__bf16)v;
            }
        }
    }
}

// ---------------------------------------------------------------------------
// value [8][2048][256] fp32 -> vt [8][256][2048] bf16 (unchanged)
// ---------------------------------------------------------------------------
__global__ __launch_bounds__(256) void k_vt(const float* __restrict__ V, __bf16* __restrict__ vt) {
    __shared__ __bf16 tile[64][72];
    const int t = threadIdx.x;
    const int b = blockIdx.z, s0 = blockIdx.x * 64, v0 = blockIdx.y * 64;
#pragma unroll
    for (int i = 0; i < 4; ++i) {
        int idx = t + i * 256;
        int r = idx >> 4, c4 = idx & 15;
        float4 x = *(const float4*)(V + ((size_t)b * SEQ + s0 + r) * DV + v0 + c4 * 4);
        *(bf16x4*)&tile[r][c4 * 4] = cvt4(x);
    }
    __syncthreads();
#pragma unroll
    for (int i = 0; i < 4; ++i) {
        int idx = t + i * 256;
        int v = idx >> 4, c4 = idx & 15;
        bf16x4 y;
        y[0] = tile[c4 * 4 + 0][v]; y[1] = tile[c4 * 4 + 1][v];
        y[2] = tile[c4 * 4 + 2][v]; y[3] = tile[c4 * 4 + 3][v];
        *(bf16x4*)(vt + ((size_t)b * DV + v0 + v) * SEQ + s0 + c4 * 4) = y;
    }
}

__global__ __launch_bounds__(256) void k_cvt_bf16(const float* __restrict__ src,
                                                  __bf16* __restrict__ dst, int n4) {
    int i = blockIdx.x * 256 + threadIdx.x;
    if (i < n4) {
        float4 v = *(const float4*)(src + (size_t)i * 4);
        *(bf16x4*)(dst + (size_t)i * 4) = cvt4(v);
    }
}

// ---------------------------------------------------------------------------
// Flash attention v2: KT=32 k-step, dbuf LDS via global_load_lds DMA, single
// barrier/iter. Source-side XOR swizzle -> conflict-free ds_read_b128.
// 37 KB LDS. grid 256 (64 q-rows/wg, 4 waves).
// ---------------------------------------------------------------------------
__global__ __launch_bounds__(256) void k_flash(const __bf16* __restrict__ r1s,
                                               const __bf16* __restrict__ r2,
                                               const __bf16* __restrict__ r3t,
                                               __bf16* __restrict__ v1) {
    __shared__ __bf16 r2s[2][32 * 128];   // [kcol][d] rows 256B, 16 chunks, s(r)=r&15
    __shared__ __bf16 r3s[2][128 * 32];   // [o][k]   rows  64B,  4 chunks, s(r)=(r>>1)&3
    __shared__ __bf16 plds[4][16][48];    // P C->A round-trip; 96B rows (16B-aligned)

    const int t = threadIdx.x, bx = blockIdx.x;
    const int b = bx >> 5, q0 = (bx & 31) * 64;
    const int w = t >> 6, l = t & 63, lrow = l & 15, lq = l >> 4;

    const __bf16* r1b = r1s + (size_t)b * SEQ * 128;
    const __bf16* r2b = r2 + (size_t)b * SEQ * 128;
    const __bf16* r3b = r3t + (size_t)b * 128 * SEQ;

    bf16x8 aQ[4];
    {
        const __bf16* p = r1b + (size_t)(q0 + w * 16 + lrow) * 128 + lq * 8;
#pragma unroll
        for (int kc = 0; kc < 4; ++kc) aQ[kc] = *(const bf16x8*)(p + kc * 32);
    }

    // per-lane DMA source pointers (2 r2 issues + 2 r3 issues per wave)
    const __bf16* p_r2[2];
    const __bf16* p_r3[2];
#pragma unroll
    for (int q1 = 0; q1 < 2; ++q1) {
        int r = 8 * w + 4 * q1 + (l >> 4);           // r2 tile row (kcol), 4 rows/issue
        int c = (l & 15) ^ (r & 15);
        p_r2[q1] = r2b + (size_t)r * 128 + c * 8;
        int r3 = 16 * (2 * w + q1) + (l >> 2);       // r3 tile row (o), 16 rows/issue
        int c3 = (l & 3) ^ ((r3 >> 1) & 3);
        p_r3[q1] = r3b + (size_t)r3 * SEQ + c3 * 8;
    }

    auto stage = [&](int bi) {
#pragma unroll
        for (int q1 = 0; q1 < 2; ++q1) {
            gl_lds16(p_r2[q1], &r2s[bi][(2 * w + q1) * 512]);
            gl_lds16(p_r3[q1], &r3s[bi][(2 * w + q1) * 512]);
            p_r2[q1] += 32 * 128;   // next k-tile: 32 kcol rows
            p_r3[q1] += 32;         // next k-window
        }
    };

    f32x4 acc[8];
#pragma unroll
    for (int i = 0; i < 8; ++i) acc[i] = f32x4{0.f, 0.f, 0.f, 0.f};
    float mrow[4] = {-INFINITY, -INFINITY, -INFINITY, -INFINITY};
    float lsum[4] = {0.f, 0.f, 0.f, 0.f};

    stage(0);
    for (int it = 0; it < 64; ++it) {
        __syncthreads();                       // compiler drains vmcnt here -> cur tile ready
        if (it + 1 < 64) stage((it + 1) & 1);  // prefetch in flight across compute
        const __bf16* R2 = &r2s[it & 1][0];
        const __bf16* R3 = &r3s[it & 1][0];

        // S = r1 . r2^T  (16q x 32k per wave)
        f32x4 sc[2];
#pragma unroll
        for (int ct = 0; ct < 2; ++ct) {
            f32x4 s = f32x4{0.f, 0.f, 0.f, 0.f};
#pragma unroll
            for (int kc = 0; kc < 4; ++kc) {
                int p = (kc * 4 + lq) ^ lrow;
                bf16x8 bb = *(const bf16x8*)&R2[(ct * 16 + lrow) * 128 + p * 8];
                s = MFMA16(aQ[kc], bb, s);
            }
            sc[ct] = s;
        }

        // online softmax (rows in lanes sharing lq)
        float pm[4], ps[4], al[4];
#pragma unroll
        for (int j = 0; j < 4; ++j) pm[j] = fmaxf(sc[0][j], sc[1][j]);
#pragma unroll
        for (int off = 1; off <= 8; off <<= 1)
#pragma unroll
            for (int j = 0; j < 4; ++j) pm[j] = fmaxf(pm[j], __shfl_xor(pm[j], off, 64));
#pragma unroll
        for (int j = 0; j < 4; ++j) {
            float mn = fmaxf(mrow[j], pm[j]);
            al[j] = __expf(mrow[j] - mn);
            mrow[j] = mn;
            ps[j] = 0.f;
        }
        float pr[2][4];
#pragma unroll
        for (int ct = 0; ct < 2; ++ct)
#pragma unroll
            for (int j = 0; j < 4; ++j) {
                float p = __expf(sc[ct][j] - mrow[j]);
                pr[ct][j] = p;
                ps[j] += p;
            }
#pragma unroll
        for (int off = 1; off <= 8; off <<= 1)
#pragma unroll
            for (int j = 0; j < 4; ++j) ps[j] += __shfl_xor(ps[j], off, 64);
#pragma unroll
        for (int j = 0; j < 4; ++j) lsum[j] = lsum[j] * al[j] + ps[j];
#pragma unroll
        for (int ot = 0; ot < 8; ++ot)
#pragma unroll
            for (int j = 0; j < 4; ++j) acc[ot][j] *= al[j];

        // P: C-layout -> LDS -> A-layout (wave-local)
#pragma unroll
        for (int ct = 0; ct < 2; ++ct)
#pragma unroll
            for (int j = 0; j < 4; ++j)
                plds[w][lq * 4 + j][ct * 16 + lrow] = (__bf16)pr[ct][j];
        __builtin_amdgcn_s_waitcnt(0xc07f);  // lgkmcnt(0) only — keep DMA prefetch in flight
        bf16x8 pA = *(const bf16x8*)&plds[w][lrow][lq * 8];

#pragma unroll
        for (int ot = 0; ot < 8; ++ot) {
            int p = lq ^ ((lrow >> 1) & 3);
            bf16x8 bb = *(const bf16x8*)&R3[(ot * 16 + lrow) * 32 + p * 8];
            acc[ot] = MFMA16(pA, bb, acc[ot]);
        }
    }

#pragma unroll
    for (int ot = 0; ot < 8; ++ot)
#pragma unroll
        for (int j = 0; j < 4; ++j) {
            int q = q0 + w * 16 + lq * 4 + j;
            float v = acc[ot][j] / lsum[j];
            v1[((size_t)b * SEQ + q) * 128 + ot * 16 + lrow] = (__bf16)v;
        }
}

// ---------------------------------------------------------------------------
// out = mask@value + (P@r3)@Wout^T.  v2: 32-row tiles (grid 512 -> 2 wg/CU),
// BK=32, dbuf DMA staging, swizzled. 40 KB LDS.
// ---------------------------------------------------------------------------
__global__ __launch_bounds__(256) void k_out(const float* __restrict__ mask,
                                             const __bf16* __restrict__ vtb,
                                             const __bf16* __restrict__ v1,
                                             const __bf16* __restrict__ wob,
                                             float* __restrict__ out) {
    __shared__ float mbuf[2][32 * 32];    // [q][k] fp32 rows 128B, 8 chunks, s(r)=r&7
    __shared__ __bf16 vbuf[2][256 * 32];  // [v][k] bf16 rows 64B, 4 chunks, s(r)=(r>>1)&3

    const int t = threadIdx.x;
    const int m0 = blockIdx.x * 32;
    const int b = m0 >> 11, q0 = m0 & 2047;
    const int w = t >> 6, l = t & 63, lrow = l & 15, lq = l >> 4;
    const int rg = w & 1, ch = w >> 1;   // wave -> 16-row group x 128-col half

    f32x4 acc[8];
#pragma unroll
    for (int i = 0; i < 8; ++i) acc[i] = f32x4{0.f, 0.f, 0.f, 0.f};

    const float* p_m;
    {
        int r = 8 * w + (l >> 3);                 // mask tile row, 8 rows/issue
        int c = (l & 7) ^ (r & 7);
        p_m = mask + ((size_t)b * SEQ + q0 + r) * SEQ + c * 4;
    }
    const __bf16* p_v[4];
#pragma unroll
    for (int q1 = 0; q1 < 4; ++q1) {
        int r = 16 * (4 * w + q1) + (l >> 2);     // vt tile row, 16 rows/issue
        int c = (l & 3) ^ ((r >> 1) & 3);
        p_v[q1] = vtb + ((size_t)b * DV + r) * SEQ + c * 8;
    }

    auto stage = [&](int bi) {
        gl_lds16(p_m, &mbuf[bi][w * 256]);
        p_m += 32;
#pragma unroll
        for (int q1 = 0; q1 < 4; ++q1) {
            gl_lds16(p_v[q1], &vbuf[bi][(4 * w + q1) * 512]);
            p_v[q1] += 32;
        }
    };

    stage(0);
    for (int it = 0; it < 64; ++it) {
        __syncthreads();
        if (it + 1 < 64) stage((it + 1) & 1);
        const float* M = &mbuf[it & 1][0];
        const __bf16* V = &vbuf[it & 1][0];

        // A-frag: mask fp32 -> bf16 (8 k-elems/lane = chunks lq*2, lq*2+1)
        int p0 = (lq * 2) ^ (lrow & 7);
        int p1 = (lq * 2 + 1) ^ (lrow & 7);
        float4 f0 = *(const float4*)&M[(rg * 16 + lrow) * 32 + p0 * 4];
        float4 f1 = *(const float4*)&M[(rg * 16 + lrow) * 32 + p1 * 4];
        bf16x8 aM;
        aM[0] = (__bf16)f0.x; aM[1] = (__bf16)f0.y; aM[2] = (__bf16)f0.z; aM[3] = (__bf16)f0.w;
        aM[4] = (__bf16)f1.x; aM[5] = (__bf16)f1.y; aM[6] = (__bf16)f1.z; aM[7] = (__bf16)f1.w;

        int pv = lq ^ ((lrow >> 1) & 3);
#pragma unroll
        for (int vt8 = 0; vt8 < 8; ++vt8) {
            bf16x8 bb = *(const bf16x8*)&V[(ch * 128 + vt8 * 16 + lrow) * 32 + pv * 8];
            acc[vt8] = MFMA16(aM, bb, acc[vt8]);
        }
    }

    // epilogue: + v1 @ Wout^T (small, direct from global/L2)
    bf16x8 aV[4];
#pragma unroll
    for (int oc = 0; oc < 4; ++oc)
        aV[oc] = *(const bf16x8*)(v1 + (size_t)(m0 + rg * 16 + lrow) * 128 + oc * 32 + lq * 8);
#pragma unroll
    for (int vt8 = 0; vt8 < 8; ++vt8) {
#pragma unroll
        for (int oc = 0; oc < 4; ++oc) {
            bf16x8 bb = *(const bf16x8*)(wob + (size_t)(ch * 128 + vt8 * 16 + lrow) * 128 + oc * 32 + lq * 8);
            acc[vt8] = MFMA16(aV[oc], bb, acc[vt8]);
        }
    }

#pragma unroll
    for (int vt8 = 0; vt8 < 8; ++vt8)
#pragma unroll
        for (int j = 0; j < 4; ++j) {
            int gq = m0 + rg * 16 + lq * 4 + j;
            out[(size_t)gq * 256 + ch * 128 + vt8 * 16 + lrow] = acc[vt8][j];
        }
}

// ---------------------------------------------------------------------------
extern "C" void kernel_launch(void* const* d_in, const int* in_sizes, int n_in,
                              void* d_out, int out_size, void* d_ws, size_t ws_size,
                              hipStream_t stream) {
    const float* q    = (const float*)d_in[0];
    const float* k    = (const float*)d_in[1];
    const float* v    = (const float*)d_in[2];
    const float* mask = (const float*)d_in[3];
    const float* W0   = (const float*)d_in[4];
    const float* W1   = (const float*)d_in[5];
    const float* W2   = (const float*)d_in[6];
    const float* Wout = (const float*)d_in[7];
    float* out = (float*)d_out;

    char* ws = (char*)d_ws;
    __bf16* r1s = (__bf16*)(ws);                  // [8][2048][128] bf16 (pre-scaled 4.5)
    __bf16* r2b = (__bf16*)(ws + (4ull << 20));   // [8][2048][128] bf16
    __bf16* r3t = (__bf16*)(ws + (8ull << 20));   // [8][128][2048] bf16 (transposed)
    __bf16* vtb = (__bf16*)(ws + (12ull << 20));  // [8][256][2048] bf16 (transposed)
    __bf16* wob = (__bf16*)(ws + (20ull << 20));  // [256][128] bf16
    __bf16* v1b = (__bf16*)(ws + (21ull << 20));  // [8][2048][128] bf16

    k_proj<128, 0><<<256, 256, 0, stream>>>(q, W0, r1s, QK_SCALE);
    k_proj<128, 0><<<256, 256, 0, stream>>>(k, W1, r2b, 1.0f);
    k_proj<256, 1><<<256, 256, 0, stream>>>(v, W2, r3t, 1.0f);
    k_vt<<<dim3(32, 4, 8), 256, 0, stream>>>(v, vtb);
    k_cvt_bf16<<<32, 256, 0, stream>>>(Wout, wob, 8192);
    k_flash<<<256, 256, 0, stream>>>(r1s, r2b, r3t, v1b);
    k_out<<<512, 256, 0, stream>>>(mask, vtb, v1b, wob, out);
}